// Round 8
// baseline (119.017 us; speedup 1.0000x reference)
//
#include <hip/hip_runtime.h>
#include <math.h>

#define B 8
#define NPTS 4096
#define QPT 8           // queries per thread in chamfer (4 v2f pairs)
#define THREADS 256

typedef float v2f __attribute__((ext_vector_type(2)));

__device__ __forceinline__ float min3f(float a, float b, float c) {
  return fminf(fminf(a, b), c);   // fuses to v_min3_f32
}

#if __has_builtin(__builtin_elementwise_fma)
__device__ __forceinline__ v2f fma2(v2f a, v2f b, v2f c) {
  return __builtin_elementwise_fma(a, b, c);   // -> v_pk_fma_f32
}
#else
__device__ __forceinline__ v2f fma2(v2f a, v2f b, v2f c) {
  v2f r; r.x = __builtin_fmaf(a.x, b.x, c.x); r.y = __builtin_fmaf(a.y, b.y, c.y);
  return r;
}
#endif

__device__ __forceinline__ v2f min2(v2f a, v2f b) {
#if __has_builtin(__builtin_elementwise_min)
  return __builtin_elementwise_min(a, b);
#else
  v2f r; r.x = fminf(a.x, b.x); r.y = fminf(a.y, b.y); return r;
#endif
}

// ws layout: [partial: 2*B*S*NPTS f][sums64: 64 f][h1p: 64*256 f][h2p: 16*128 f]
// partial[((dir*B+b)*S + split)*NPTS + q]
// sums64[(dir*B+b)*2 + {0:min,1:soft}]; sums64[32] = k2 done-counter (u32)

// ======== K1: 32*S chamfer blocks; blocks 0..63 also do MLP-L1 first ======
// grid = 1024 for S=32 -> exactly 4 blocks/CU, single occupancy wave.
template<int S, int LOG2S>
__global__ __launch_bounds__(THREADS, 4) void k1_kernel(
    const float* __restrict__ pred, const float* __restrict__ targ,
    const float* __restrict__ x, const float* __restrict__ W1,
    float* __restrict__ partial, float* __restrict__ sums64,
    float* __restrict__ h1p) {
  constexpr int REFS = NPTS / S;   // 128 for S=32
  const int id = blockIdx.x;
  const int tid = threadIdx.x;

  __shared__ float4 refs[REFS];
  __shared__ float xs[64];

  if (id < 64) {
    // ---- MLP layer-1 rider: h1p[(b*8+kc)*256+j] = sum_k x[b,k]W1[k,j]
    if (id == 0 && tid < 64) sums64[tid] = 0.f;   // zero sums + done-counter
    int b = id >> 3, kc = id & 7;
    if (tid < 64) xs[tid] = x[b * 512 + kc * 64 + tid];
    __syncthreads();
    float acc = 0.f;
    const float* w = W1 + (size_t)(kc * 64) * 256 + tid;
#pragma unroll 8
    for (int k = 0; k < 64; ++k) acc = fmaf(xs[k], w[k * 256], acc);
    h1p[(b * 8 + kc) * 256 + tid] = acc;
    __syncthreads();
  }

  // ---- chamfer split-partial mins (every block, id = cid)
  int split  = id & (S - 1);
  int qchunk = (id >> LOG2S) & 1;
  int b      = (id >> (LOG2S + 1)) & 7;
  int dir    = id >> (LOG2S + 4);
  const float* qp = dir ? targ : pred;
  const float* rp = dir ? pred : targ;

  const float* rb = rp + ((size_t)b * NPTS + (size_t)split * REFS) * 3;
  for (int i = tid; i < REFS; i += THREADS) {
    float xx = rb[i * 3 + 0], yy = rb[i * 3 + 1], zz = rb[i * 3 + 2];
    refs[i] = make_float4(xx, yy, zz, 0.5f * (xx * xx + yy * yy + zz * zz));
  }

  const float* qb = qp + (size_t)b * NPTS * 3;
  int q0 = qchunk * (QPT * THREADS) + tid;
  float qn[QPT];
  v2f nqx[QPT / 2], nqy[QPT / 2], nqz[QPT / 2], vmin2[QPT / 2];
#pragma unroll
  for (int p = 0; p < QPT / 2; ++p) {
    int qa = q0 + (2 * p) * THREADS, qbi = q0 + (2 * p + 1) * THREADS;
    float ax = qb[qa * 3 + 0], ay = qb[qa * 3 + 1], az = qb[qa * 3 + 2];
    float bx = qb[qbi * 3 + 0], by = qb[qbi * 3 + 1], bz = qb[qbi * 3 + 2];
    qn[2 * p]     = fmaf(ax, ax, fmaf(ay, ay, az * az));
    qn[2 * p + 1] = fmaf(bx, bx, fmaf(by, by, bz * bz));
    nqx[p] = (v2f){-ax, -bx};
    nqy[p] = (v2f){-ay, -by};
    nqz[p] = (v2f){-az, -bz};
    vmin2[p] = (v2f){3.4e38f, 3.4e38f};
  }
  __syncthreads();

  // s = -qx*tx + (-qy*ty + (-qz*tz + 0.5|t|^2))  — same per-element fma
  // order as before; two queries per v_pk_fma_f32 (t broadcast via op_sel).
  for (int j = 0; j < REFS; j += 8) {
    float4 t[8];
#pragma unroll
    for (int u = 0; u < 8; ++u) t[u] = refs[j + u];
#pragma unroll
    for (int p = 0; p < QPT / 2; ++p) {
      v2f s[8];
#pragma unroll
      for (int u = 0; u < 8; ++u) {
        v2f tx = (v2f){t[u].x, t[u].x};
        v2f ty = (v2f){t[u].y, t[u].y};
        v2f tz = (v2f){t[u].z, t[u].z};
        v2f tw = (v2f){t[u].w, t[u].w};
        s[u] = fma2(nqx[p], tx, fma2(nqy[p], ty, fma2(nqz[p], tz, tw)));
      }
      v2f m01 = min2(s[0], s[1]), m23 = min2(s[2], s[3]);
      v2f m45 = min2(s[4], s[5]), m67 = min2(s[6], s[7]);
      vmin2[p] = min2(vmin2[p], min2(min2(m01, m23), min2(m45, m67)));
    }
  }

  size_t base = (((size_t)dir * B + b) * S + split) * NPTS;
#pragma unroll
  for (int p = 0; p < QPT / 2; ++p) {
    partial[base + q0 + (2 * p) * THREADS] =
        fmaf(2.f, vmin2[p].x, qn[2 * p]);
    partial[base + q0 + (2 * p + 1) * THREADS] =
        fmaf(2.f, vmin2[p].y, qn[2 * p + 1]);
  }
}

// ======== K2: 256 reduce + 16 MLP-L2 blocks; fence-light last-block tail ===
// (R7-proven.) Reduce blocks emit only atomics, ordered by s_waitcnt
// vmcnt(0); only the 16 MLP blocks fence; tail does one acquire fence.
template<int S>
__global__ __launch_bounds__(THREADS) void k2_kernel(
    const float* __restrict__ partial, float* __restrict__ sums64,
    const float* __restrict__ h1p, const float* __restrict__ b1,
    const float* __restrict__ W2, const float* __restrict__ b2,
    const float* __restrict__ W3, const float* __restrict__ b3,
    const int* __restrict__ labels, const float* __restrict__ wgt,
    float* __restrict__ out) {
  constexpr int NBLK = 272;
  const int id = blockIdx.x;
  const int tid = threadIdx.x;
  __shared__ float red[8];
  __shared__ float hs[128];
  __shared__ bool is_last;

  if (id >= 256) {
    // ---- MLP-L2 partials: h2p[(b*2+half)*128+j] over k in [half*128,+128)
    int lid = id - 256;
    int b = lid >> 1, half = lid & 1;
    if (tid < 128) {
      int k = half * 128 + tid;
      float a = b1[k];
#pragma unroll
      for (int p = 0; p < 8; ++p) a += h1p[(b * 8 + p) * 256 + k];
      hs[tid] = fmaxf(a, 0.f);
    }
    __syncthreads();
    if (tid < 128) {
      float acc = 0.f;
      const float* w = W2 + (size_t)(half * 128) * 128 + tid;
#pragma unroll 8
      for (int k = 0; k < 128; ++k) acc = fmaf(hs[k], w[k * 128], acc);
      float* h2p = sums64 + 64 + 64 * 256;
      h2p[(b * 2 + half) * 128 + tid] = acc;
    }
    __threadfence();          // release h2p stores (16 blocks only)
    __syncthreads();
    if (tid == 0) {
      unsigned t = atomicAdd((unsigned*)(sums64 + 32), 1u);
      is_last = (t == NBLK - 1);
    }
  } else {
    // ---- reduce: min over S splits (batched loads), sum min and exp
    int chunk = id & 15;
    int b   = (id >> 4) & 7;
    int dir = id >> 7;
    size_t pb = ((size_t)dir * B + b) * S * NPTS;
    int q = chunk * 256 + tid;

    float v[S];
#pragma unroll
    for (int s = 0; s < S; ++s)
      v[s] = partial[pb + (size_t)s * NPTS + q];
    float m = v[0];
#pragma unroll
    for (int s = 1; s < S; ++s) m = fminf(m, v[s]);
    float s_min = m;
    float s_soft = __expf(-5000.0f * m);   // 1/(2*sigma^2) = 5000

    for (int off = 32; off > 0; off >>= 1) {
      s_min  += __shfl_down(s_min,  off);
      s_soft += __shfl_down(s_soft, off);
    }
    int wave = tid >> 6, lane = tid & 63;
    if (lane == 0) { red[wave * 2] = s_min; red[wave * 2 + 1] = s_soft; }
    __syncthreads();
    if (tid == 0) {
      float a = 0.f, c = 0.f;
      for (int wv = 0; wv < 4; ++wv) { a += red[wv * 2]; c += red[wv * 2 + 1]; }
      atomicAdd(&sums64[(dir * B + b) * 2 + 0], a);
      atomicAdd(&sums64[(dir * B + b) * 2 + 1], c);
      // order the sums-adds before the counter-add without an L2 writeback
      asm volatile("s_waitcnt vmcnt(0)" ::: "memory");
      unsigned t = atomicAdd((unsigned*)(sums64 + 32), 1u);
      is_last = (t == NBLK - 1);
    }
  }
  __syncthreads();
  if (!is_last) return;
  __threadfence();                                   // acquire (1 block)

  // ---- tail (last block): L2-combine + L3 + softmax/NLL + final combine
  __shared__ float h2s[8 * 128];
  __shared__ float lg[48];
  __shared__ float nlls[8];
  volatile const float* vh2 = (volatile const float*)(sums64 + 64 + 64 * 256);

  for (int i = tid; i < 1024; i += THREADS) {
    int bb = i >> 7, j = i & 127;
    float a = b2[j] + vh2[(bb * 2 + 0) * 128 + j] + vh2[(bb * 2 + 1) * 128 + j];
    h2s[i] = fmaxf(a, 0.f);
  }
  __syncthreads();
  if (tid < 48) {
    int bb = tid / 6, d = tid % 6;
    float acc = b3[d];
#pragma unroll 8
    for (int k = 0; k < 128; ++k)
      acc = fmaf(h2s[bb * 128 + k], W3[k * 6 + d], acc);
    lg[tid] = acc;
  }
  __syncthreads();
  if (tid < 8) {
    int bb = tid;
    float mx = lg[bb * 6];
    for (int d = 1; d < 6; ++d) mx = fmaxf(mx, lg[bb * 6 + d]);
    float se = 0.f;
    for (int d = 0; d < 6; ++d) se += __expf(lg[bb * 6 + d] - mx);
    int lab = labels[bb];
    nlls[bb] = -(lg[bb * 6 + lab] - mx - __logf(se));
  }
  __syncthreads();
  if (tid == 0) {
    volatile const float* vs = (volatile const float*)sums64;
    float chamfer = 0.f, prec = 0.f, rec = 0.f, dsw = 0.f, dom = 0.f;
    for (int bb = 0; bb < B; ++bb) {
      float sa  = vs[(0 * B + bb) * 2 + 0];
      float ssa = vs[(0 * B + bb) * 2 + 1];
      float sb  = vs[(1 * B + bb) * 2 + 0];
      float ssb = vs[(1 * B + bb) * 2 + 1];
      float ma = sa / 4096.f, mb = sb / 4096.f;
      float p = ssa / 4096.f, r = ssb / 4096.f;
      chamfer += ma + mb;
      prec += p; rec += r;
      float f_i = 2.f * p * r / (p + r + 1e-8f);
      float loss_i = ma + mb + 0.1f * (1.f - f_i);
      dsw += wgt[bb] * loss_i;
      dom += nlls[bb];
    }
    chamfer *= (1.f / B); prec *= (1.f / B); rec *= (1.f / B);
    dsw *= (1.f / B); dom *= (1.f / B);
    float fscore = 2.f * prec * rec / (prec + rec + 1e-8f);
    float task = chamfer + 0.1f * (1.f - fscore);
    out[0] = 1.0f * task + 0.1f * dom + dsw;
  }
}

// ======================= host dispatch ==================================
template<int S, int LOG2S>
static void run_pipeline(const float* pred, const float* targ, const float* x,
                         const float* wgt, const float* W1, const float* b1,
                         const float* W2, const float* b2, const float* W3,
                         const float* b3, const int* labels, float* out,
                         char* ws, hipStream_t stream) {
  float* partial = (float*)ws;
  float* sums64  = partial + (size_t)2 * B * S * NPTS;
  float* h1p     = sums64 + 64;

  hipLaunchKernelGGL((k1_kernel<S, LOG2S>), dim3(32 * S), dim3(THREADS),
                     0, stream, pred, targ, x, W1, partial, sums64, h1p);
  hipLaunchKernelGGL((k2_kernel<S>), dim3(272), dim3(THREADS), 0, stream,
                     partial, sums64, h1p, b1, W2, b2, W3, b3, labels, wgt,
                     out);
}

extern "C" void kernel_launch(void* const* d_in, const int* in_sizes, int n_in,
                              void* d_out, int out_size, void* d_ws, size_t ws_size,
                              hipStream_t stream) {
  const float* pred   = (const float*)d_in[0];
  const float* targ   = (const float*)d_in[1];
  const float* x      = (const float*)d_in[2];
  const float* wgt    = (const float*)d_in[3];
  const float* W1     = (const float*)d_in[4];
  const float* b1     = (const float*)d_in[5];
  const float* W2     = (const float*)d_in[6];
  const float* b2     = (const float*)d_in[7];
  const float* W3     = (const float*)d_in[8];
  const float* b3     = (const float*)d_in[9];
  const int*   labels = (const int*)d_in[10];
  float* out = (float*)d_out;
  char* ws = (char*)d_ws;

  auto need = [](int S) {
    return ((size_t)2 * B * S * NPTS + 64 + 64 * 256 + 16 * 128) * sizeof(float);
  };
  if (ws_size >= need(32))
    run_pipeline<32, 5>(pred, targ, x, wgt, W1, b1, W2, b2, W3, b3, labels,
                        out, ws, stream);
  else if (ws_size >= need(16))
    run_pipeline<16, 4>(pred, targ, x, wgt, W1, b1, W2, b2, W3, b3, labels,
                        out, ws, stream);
  else
    run_pipeline<8, 3>(pred, targ, x, wgt, W1, b1, W2, b2, W3, b3, labels,
                       out, ws, stream);
}

// Round 9
// 118.825 us; speedup vs baseline: 1.0016x; 1.0016x over previous
//
#include <hip/hip_runtime.h>
#include <math.h>

#define B 8
#define NPTS 4096
#define QPT 8           // queries per thread in chamfer (4 v2f pairs)
#define THREADS 256

typedef float v2f __attribute__((ext_vector_type(2)));

__device__ __forceinline__ float min3f(float a, float b, float c) {
  return fminf(fminf(a, b), c);   // fuses to v_min3_f32
}

#if __has_builtin(__builtin_elementwise_fma)
__device__ __forceinline__ v2f fma2(v2f a, v2f b, v2f c) {
  return __builtin_elementwise_fma(a, b, c);   // -> v_pk_fma_f32
}
#else
__device__ __forceinline__ v2f fma2(v2f a, v2f b, v2f c) {
  v2f r; r.x = __builtin_fmaf(a.x, b.x, c.x); r.y = __builtin_fmaf(a.y, b.y, c.y);
  return r;
}
#endif

__device__ __forceinline__ v2f min2(v2f a, v2f b) {
#if __has_builtin(__builtin_elementwise_min)
  return __builtin_elementwise_min(a, b);
#else
  v2f r; r.x = fminf(a.x, b.x); r.y = fminf(a.y, b.y); return r;
#endif
}

// ws layout: [partial: 2*B*S*NPTS f][sums64: 64 f][h1p: 64*256 f][h2p: 16*128 f]
// partial[((dir*B+b)*S + split)*NPTS + q]
// sums64[(dir*B+b)*2 + {0:min,1:soft}] (plain stores, one writer each)
// sums64[32] = k2 done-counter (u32)

// ======== K1: 32*S chamfer blocks; blocks 0..63 also do MLP-L1 first ======
// (R8 kernel verbatim; measured equal to R0's d1.)
template<int S, int LOG2S>
__global__ __launch_bounds__(THREADS, 4) void k1_kernel(
    const float* __restrict__ pred, const float* __restrict__ targ,
    const float* __restrict__ x, const float* __restrict__ W1,
    float* __restrict__ partial, float* __restrict__ sums64,
    float* __restrict__ h1p) {
  constexpr int REFS = NPTS / S;   // 128 for S=32
  const int id = blockIdx.x;
  const int tid = threadIdx.x;

  __shared__ float4 refs[REFS];
  __shared__ float xs[64];

  if (id < 64) {
    // ---- MLP layer-1 rider: h1p[(b*8+kc)*256+j] = sum_k x[b,k]W1[k,j]
    if (id == 0 && tid < 64) sums64[tid] = 0.f;   // zero sums + done-counter
    int b = id >> 3, kc = id & 7;
    if (tid < 64) xs[tid] = x[b * 512 + kc * 64 + tid];
    __syncthreads();
    float acc = 0.f;
    const float* w = W1 + (size_t)(kc * 64) * 256 + tid;
#pragma unroll 8
    for (int k = 0; k < 64; ++k) acc = fmaf(xs[k], w[k * 256], acc);
    h1p[(b * 8 + kc) * 256 + tid] = acc;
    __syncthreads();
  }

  // ---- chamfer split-partial mins (every block, id = cid)
  int split  = id & (S - 1);
  int qchunk = (id >> LOG2S) & 1;
  int b      = (id >> (LOG2S + 1)) & 7;
  int dir    = id >> (LOG2S + 4);
  const float* qp = dir ? targ : pred;
  const float* rp = dir ? pred : targ;

  const float* rb = rp + ((size_t)b * NPTS + (size_t)split * REFS) * 3;
  for (int i = tid; i < REFS; i += THREADS) {
    float xx = rb[i * 3 + 0], yy = rb[i * 3 + 1], zz = rb[i * 3 + 2];
    refs[i] = make_float4(xx, yy, zz, 0.5f * (xx * xx + yy * yy + zz * zz));
  }

  const float* qb = qp + (size_t)b * NPTS * 3;
  int q0 = qchunk * (QPT * THREADS) + tid;
  float qn[QPT];
  v2f nqx[QPT / 2], nqy[QPT / 2], nqz[QPT / 2], vmin2[QPT / 2];
#pragma unroll
  for (int p = 0; p < QPT / 2; ++p) {
    int qa = q0 + (2 * p) * THREADS, qbi = q0 + (2 * p + 1) * THREADS;
    float ax = qb[qa * 3 + 0], ay = qb[qa * 3 + 1], az = qb[qa * 3 + 2];
    float bx = qb[qbi * 3 + 0], by = qb[qbi * 3 + 1], bz = qb[qbi * 3 + 2];
    qn[2 * p]     = fmaf(ax, ax, fmaf(ay, ay, az * az));
    qn[2 * p + 1] = fmaf(bx, bx, fmaf(by, by, bz * bz));
    nqx[p] = (v2f){-ax, -bx};
    nqy[p] = (v2f){-ay, -by};
    nqz[p] = (v2f){-az, -bz};
    vmin2[p] = (v2f){3.4e38f, 3.4e38f};
  }
  __syncthreads();

  for (int j = 0; j < REFS; j += 8) {
    float4 t[8];
#pragma unroll
    for (int u = 0; u < 8; ++u) t[u] = refs[j + u];
#pragma unroll
    for (int p = 0; p < QPT / 2; ++p) {
      v2f s[8];
#pragma unroll
      for (int u = 0; u < 8; ++u) {
        v2f tx = (v2f){t[u].x, t[u].x};
        v2f ty = (v2f){t[u].y, t[u].y};
        v2f tz = (v2f){t[u].z, t[u].z};
        v2f tw = (v2f){t[u].w, t[u].w};
        s[u] = fma2(nqx[p], tx, fma2(nqy[p], ty, fma2(nqz[p], tz, tw)));
      }
      v2f m01 = min2(s[0], s[1]), m23 = min2(s[2], s[3]);
      v2f m45 = min2(s[4], s[5]), m67 = min2(s[6], s[7]);
      vmin2[p] = min2(vmin2[p], min2(min2(m01, m23), min2(m45, m67)));
    }
  }

  size_t base = (((size_t)dir * B + b) * S + split) * NPTS;
#pragma unroll
  for (int p = 0; p < QPT / 2; ++p) {
    partial[base + q0 + (2 * p) * THREADS] =
        fmaf(2.f, vmin2[p].x, qn[2 * p]);
    partial[base + q0 + (2 * p + 1) * THREADS] =
        fmaf(2.f, vmin2[p].y, qn[2 * p + 1]);
  }
}

// ======== K2: 16 reduce blocks (one per dir,b; plain stores) + 16 MLP-L2 ===
// Counter has only 32 increments; 32 release fences + 1 acquire total.
template<int S>
__global__ __launch_bounds__(THREADS) void k2_kernel(
    const float* __restrict__ partial, float* __restrict__ sums64,
    const float* __restrict__ h1p, const float* __restrict__ b1,
    const float* __restrict__ W2, const float* __restrict__ b2,
    const float* __restrict__ W3, const float* __restrict__ b3,
    const int* __restrict__ labels, const float* __restrict__ wgt,
    float* __restrict__ out) {
  constexpr int NBLK = 32;
  const int id = blockIdx.x;
  const int tid = threadIdx.x;
  __shared__ float red[8];
  __shared__ float hs[128];
  __shared__ bool is_last;

  if (id >= 16) {
    // ---- MLP-L2 partials: h2p[(b*2+half)*128+j] over k in [half*128,+128)
    int lid = id - 16;
    int b = lid >> 1, half = lid & 1;
    if (tid < 128) {
      int k = half * 128 + tid;
      float a = b1[k];
#pragma unroll
      for (int p = 0; p < 8; ++p) a += h1p[(b * 8 + p) * 256 + k];
      hs[tid] = fmaxf(a, 0.f);
    }
    __syncthreads();
    if (tid < 128) {
      float acc = 0.f;
      const float* w = W2 + (size_t)(half * 128) * 128 + tid;
#pragma unroll 8
      for (int k = 0; k < 128; ++k) acc = fmaf(hs[k], w[k * 128], acc);
      float* h2p = sums64 + 64 + 64 * 256;
      h2p[(b * 2 + half) * 128 + tid] = acc;
    }
  } else {
    // ---- reduce: block id owns (dir*B+b) = id entirely. 16 q-batches,
    // batched v[S] strided loads (coalesced 1KB/wave-inst), min-tree,
    // accumulate sum-of-min and sum-of-exp. Plain store — no atomics.
    size_t pb = (size_t)id * S * NPTS;
    float s_min = 0.f, s_soft = 0.f;
    for (int qq = 0; qq < NPTS / THREADS; ++qq) {
      int q = qq * THREADS + tid;
      float v[S];
#pragma unroll
      for (int s = 0; s < S; ++s)
        v[s] = partial[pb + (size_t)s * NPTS + q];
      float m = v[0];
#pragma unroll
      for (int s = 1; s < S; ++s) m = fminf(m, v[s]);
      s_min += m;
      s_soft += __expf(-5000.0f * m);   // 1/(2*sigma^2) = 5000
    }
    for (int off = 32; off > 0; off >>= 1) {
      s_min  += __shfl_down(s_min,  off);
      s_soft += __shfl_down(s_soft, off);
    }
    int wave = tid >> 6, lane = tid & 63;
    if (lane == 0) { red[wave * 2] = s_min; red[wave * 2 + 1] = s_soft; }
    __syncthreads();
    if (tid == 0) {
      float a = 0.f, c = 0.f;
      for (int wv = 0; wv < 4; ++wv) { a += red[wv * 2]; c += red[wv * 2 + 1]; }
      sums64[id * 2 + 0] = a;      // single writer — plain store
      sums64[id * 2 + 1] = c;
    }
  }

  // ---- done-counter handshake (stores -> fence -> sync -> counter)
  __threadfence();
  __syncthreads();
  if (tid == 0) {
    unsigned t = atomicAdd((unsigned*)(sums64 + 32), 1u);
    is_last = (t == NBLK - 1);
  }
  __syncthreads();
  if (!is_last) return;
  __threadfence();                                   // acquire (1 block)

  // ---- tail (last block): L2-combine + L3 + softmax/NLL + final combine
  __shared__ float h2s[8 * 128];
  __shared__ float lg[48];
  __shared__ float nlls[8];
  volatile const float* vh2 = (volatile const float*)(sums64 + 64 + 64 * 256);

  for (int i = tid; i < 1024; i += THREADS) {
    int bb = i >> 7, j = i & 127;
    float a = b2[j] + vh2[(bb * 2 + 0) * 128 + j] + vh2[(bb * 2 + 1) * 128 + j];
    h2s[i] = fmaxf(a, 0.f);
  }
  __syncthreads();
  if (tid < 48) {
    int bb = tid / 6, d = tid % 6;
    float acc = b3[d];
#pragma unroll 8
    for (int k = 0; k < 128; ++k)
      acc = fmaf(h2s[bb * 128 + k], W3[k * 6 + d], acc);
    lg[tid] = acc;
  }
  __syncthreads();
  if (tid < 8) {
    int bb = tid;
    float mx = lg[bb * 6];
    for (int d = 1; d < 6; ++d) mx = fmaxf(mx, lg[bb * 6 + d]);
    float se = 0.f;
    for (int d = 0; d < 6; ++d) se += __expf(lg[bb * 6 + d] - mx);
    int lab = labels[bb];
    nlls[bb] = -(lg[bb * 6 + lab] - mx - __logf(se));
  }
  __syncthreads();
  if (tid == 0) {
    volatile const float* vs = (volatile const float*)sums64;
    float chamfer = 0.f, prec = 0.f, rec = 0.f, dsw = 0.f, dom = 0.f;
    for (int bb = 0; bb < B; ++bb) {
      float sa  = vs[(0 * B + bb) * 2 + 0];
      float ssa = vs[(0 * B + bb) * 2 + 1];
      float sb  = vs[(1 * B + bb) * 2 + 0];
      float ssb = vs[(1 * B + bb) * 2 + 1];
      float ma = sa / 4096.f, mb = sb / 4096.f;
      float p = ssa / 4096.f, r = ssb / 4096.f;
      chamfer += ma + mb;
      prec += p; rec += r;
      float f_i = 2.f * p * r / (p + r + 1e-8f);
      float loss_i = ma + mb + 0.1f * (1.f - f_i);
      dsw += wgt[bb] * loss_i;
      dom += nlls[bb];
    }
    chamfer *= (1.f / B); prec *= (1.f / B); rec *= (1.f / B);
    dsw *= (1.f / B); dom *= (1.f / B);
    float fscore = 2.f * prec * rec / (prec + rec + 1e-8f);
    float task = chamfer + 0.1f * (1.f - fscore);
    out[0] = 1.0f * task + 0.1f * dom + dsw;
  }
}

// ======================= host dispatch ==================================
template<int S, int LOG2S>
static void run_pipeline(const float* pred, const float* targ, const float* x,
                         const float* wgt, const float* W1, const float* b1,
                         const float* W2, const float* b2, const float* W3,
                         const float* b3, const int* labels, float* out,
                         char* ws, hipStream_t stream) {
  float* partial = (float*)ws;
  float* sums64  = partial + (size_t)2 * B * S * NPTS;
  float* h1p     = sums64 + 64;

  hipLaunchKernelGGL((k1_kernel<S, LOG2S>), dim3(32 * S), dim3(THREADS),
                     0, stream, pred, targ, x, W1, partial, sums64, h1p);
  hipLaunchKernelGGL((k2_kernel<S>), dim3(32), dim3(THREADS), 0, stream,
                     partial, sums64, h1p, b1, W2, b2, W3, b3, labels, wgt,
                     out);
}

extern "C" void kernel_launch(void* const* d_in, const int* in_sizes, int n_in,
                              void* d_out, int out_size, void* d_ws, size_t ws_size,
                              hipStream_t stream) {
  const float* pred   = (const float*)d_in[0];
  const float* targ   = (const float*)d_in[1];
  const float* x      = (const float*)d_in[2];
  const float* wgt    = (const float*)d_in[3];
  const float* W1     = (const float*)d_in[4];
  const float* b1     = (const float*)d_in[5];
  const float* W2     = (const float*)d_in[6];
  const float* b2     = (const float*)d_in[7];
  const float* W3     = (const float*)d_in[8];
  const float* b3     = (const float*)d_in[9];
  const int*   labels = (const int*)d_in[10];
  float* out = (float*)d_out;
  char* ws = (char*)d_ws;

  auto need = [](int S) {
    return ((size_t)2 * B * S * NPTS + 64 + 64 * 256 + 16 * 128) * sizeof(float);
  };
  if (ws_size >= need(32))
    run_pipeline<32, 5>(pred, targ, x, wgt, W1, b1, W2, b2, W3, b3, labels,
                        out, ws, stream);
  else if (ws_size >= need(16))
    run_pipeline<16, 4>(pred, targ, x, wgt, W1, b1, W2, b2, W3, b3, labels,
                        out, ws, stream);
  else
    run_pipeline<8, 3>(pred, targ, x, wgt, W1, b1, W2, b2, W3, b3, labels,
                       out, ws, stream);
}